// Round 2
// baseline (12715.402 us; speedup 1.0000x reference)
//
#include <hip/hip_runtime.h>
#include <math.h>

#define H 128
#define BST 64   // LDS buf column count (= edges/nodes per block); stride-1 lane reads, 2-way = free

__device__ __forceinline__ float silu_f(float v) {
    return v / (1.0f + __expf(-v));
}

// acc[j] += sum_k buf[k][lane] * Wu[k*H + j], k = 0..127.
// Wu is WAVE-UNIFORM (derived from readfirstlane'd wid) -> s_load weights (SGPR operand).
__device__ __forceinline__ void gemm_sgpr(const float (*__restrict__ buf)[BST],
                                          const float* __restrict__ Wu,
                                          int lane, float acc[32]) {
#pragma unroll 2
    for (int k = 0; k < H; ++k) {
        const float a = buf[k][lane];
        const float* __restrict__ wr = Wu + (size_t)k * H;
#pragma unroll
        for (int j = 0; j < 32; ++j)
            acc[j] = fmaf(a, wr[j], acc[j]);
    }
}

// wave stages features [wb, wb+32) of row `rowp` into buf[f][lane] (transposed)
__device__ __forceinline__ void stage32(const float* __restrict__ rowp, int wb, int lane,
                                        float (*__restrict__ buf)[BST]) {
#pragma unroll
    for (int c = 0; c < 8; ++c) {
        const float4 v = *(const float4*)(rowp + 4 * c);
        buf[wb + 4 * c + 0][lane] = v.x;
        buf[wb + 4 * c + 1][lane] = v.y;
        buf[wb + 4 * c + 2][lane] = v.z;
        buf[wb + 4 * c + 3][lane] = v.w;
    }
}

// ---------------- input embedding + first linear ----------------
__global__ void __launch_bounds__(256)
input_kernel(const float* __restrict__ node_scalar, const int* __restrict__ type_ids,
             const float* __restrict__ emb, const float* __restrict__ W_in,
             const float* __restrict__ b_in, float* __restrict__ hout,
             int NN, int ntypes)
{
    const int idx = blockIdx.x * 256 + threadIdx.x;
    if (idx >= NN * H) return;
    const int n = idx >> 7;
    const int f = idx & (H - 1);
    int t = type_ids[n];
    t = t < 0 ? 0 : (t >= ntypes ? ntypes - 1 : t);
    float s = b_in[f];
#pragma unroll
    for (int k = 0; k < 5; ++k) s = fmaf(node_scalar[n * 5 + k], W_in[k * H + f], s);
#pragma unroll
    for (int k = 0; k < 8; ++k) s = fmaf(emb[t * 8 + k], W_in[(5 + k) * H + f], s);
    hout[idx] = s;
}

// ---------------- per-layer edge kernel ----------------
__global__ void __launch_bounds__(256, 4)
edge_kernel(const float* __restrict__ x, const float* __restrict__ h,
            const int* __restrict__ src, const int* __restrict__ dst,
            const float* __restrict__ eW1, const float* __restrict__ eb1,
            const float* __restrict__ eW2, const float* __restrict__ eb2,
            const float* __restrict__ eW3, const float* __restrict__ eb3,
            const float* __restrict__ cW1, const float* __restrict__ cb1,
            const float* __restrict__ cW2, const float* __restrict__ cb2,
            float* __restrict__ m_aggr, float* __restrict__ dxv,
            int E)
{
    __shared__ float buf[H][BST];      // 32 KB
    __shared__ float d2s[64];
    __shared__ float cred[4][64];

    const int tid  = threadIdx.x;
    const int lane = tid & 63;
    const int wid  = __builtin_amdgcn_readfirstlane(tid >> 6);
    const int wb   = wid * 32;
    const int e0   = blockIdx.x * 64;

    int e = e0 + lane;
    const bool ev = (e < E);
    if (!ev) e = E - 1;
    const int s = src[e], d = dst[e];

    const float rx = x[3 * s + 0] - x[3 * d + 0];
    const float ry = x[3 * s + 1] - x[3 * d + 1];
    const float rz = x[3 * s + 2] - x[3 * d + 2];
    if (wid == 0) d2s[lane] = rx * rx + ry * ry + rz * rz;

    // stage h[src] features [wb,wb+32)
    stage32(h + (size_t)s * H + wb, wb, lane, buf);
    __syncthreads();

    float acc[32];
    {
        const float d2 = d2s[lane];
        const float* __restrict__ bb   = eb1 + wb;
        const float* __restrict__ w256 = eW1 + (size_t)256 * H + wb;
#pragma unroll
        for (int j = 0; j < 32; ++j) acc[j] = fmaf(d2, w256[j], bb[j]);
    }
    gemm_sgpr(buf, eW1 + wb, lane, acc);              // k = 0..127   (h_src)
    __syncthreads();

    stage32(h + (size_t)d * H + wb, wb, lane, buf);   // h[dst]
    __syncthreads();
    gemm_sgpr(buf, eW1 + (size_t)128 * H + wb, lane, acc);  // k = 128..255 (h_dst)
    __syncthreads();

#pragma unroll
    for (int j = 0; j < 32; ++j) buf[wb + j][lane] = silu_f(acc[j]);   // m1
    __syncthreads();

    {
        const float* __restrict__ bb = eb2 + wb;
#pragma unroll
        for (int j = 0; j < 32; ++j) acc[j] = bb[j];
    }
    gemm_sgpr(buf, eW2 + wb, lane, acc);
    __syncthreads();
#pragma unroll
    for (int j = 0; j < 32; ++j) buf[wb + j][lane] = silu_f(acc[j]);   // m2
    __syncthreads();

    {
        const float* __restrict__ bb = eb3 + wb;
#pragma unroll
        for (int j = 0; j < 32; ++j) acc[j] = bb[j];
    }
    gemm_sgpr(buf, eW3 + wb, lane, acc);               // m

    if (ev) {
        float* dp = &m_aggr[(size_t)s * H + wb];
#pragma unroll
        for (int j = 0; j < 32; ++j) atomicAdd(dp + j, acc[j]);
    }
    __syncthreads();
#pragma unroll
    for (int j = 0; j < 32; ++j) buf[wb + j][lane] = acc[j];           // m -> buf
    __syncthreads();

    {
        const float* __restrict__ bb = cb1 + wb;
#pragma unroll
        for (int j = 0; j < 32; ++j) acc[j] = bb[j];
    }
    gemm_sgpr(buf, cW1 + wb, lane, acc);               // coord hidden (pre-silu)

    {
        const float* __restrict__ c2 = cW2 + wb;
        float p = 0.f;
#pragma unroll
        for (int j = 0; j < 32; ++j) p = fmaf(silu_f(acc[j]), c2[j], p);
        cred[wid][lane] = p;
    }
    __syncthreads();

    if (wid == 0 && ev) {
        const float sum  = cred[0][lane] + cred[1][lane] + cred[2][lane] + cred[3][lane];
        const float coef = tanhf(sum + cb2[0]);
        float* dp = &dxv[(size_t)s * 3];
        atomicAdd(dp + 0, rx * coef);
        atomicAdd(dp + 1, ry * coef);
        atomicAdd(dp + 2, rz * coef);
    }
}

// ---------------- per-layer node kernel ----------------
__global__ void __launch_bounds__(256, 4)
node_kernel(float* __restrict__ x, const float* __restrict__ dxv,
            float* __restrict__ h, const float* __restrict__ m_aggr,
            const float* __restrict__ nW1, const float* __restrict__ nb1,
            const float* __restrict__ nW2, const float* __restrict__ nb2,
            const float* __restrict__ nW3, const float* __restrict__ nb3,
            int NN)
{
    __shared__ float buf[H][BST];

    const int tid  = threadIdx.x;
    const int lane = tid & 63;
    const int wid  = __builtin_amdgcn_readfirstlane(tid >> 6);
    const int wb   = wid * 32;
    const int n0   = blockIdx.x * 64;

    const int n = n0 + lane;
    const bool valid = (n < NN);
    const int nc = valid ? n : NN - 1;

    if (tid < 192) {
        const int nn = n0 + tid / 3;
        if (nn < NN) {
            const int c = tid % 3;
            x[(size_t)nn * 3 + c] += dxv[(size_t)nn * 3 + c];
        }
    }

    stage32(h + (size_t)nc * H + wb, wb, lane, buf);
    __syncthreads();

    float acc[32];
    {
        const float* __restrict__ bb = nb1 + wb;
#pragma unroll
        for (int j = 0; j < 32; ++j) acc[j] = bb[j];
    }
    gemm_sgpr(buf, nW1 + wb, lane, acc);               // k = 0..127 (h)
    __syncthreads();

    stage32(m_aggr + (size_t)nc * H + wb, wb, lane, buf);
    __syncthreads();
    gemm_sgpr(buf, nW1 + (size_t)128 * H + wb, lane, acc);  // k = 128..255 (m_aggr)
    __syncthreads();

#pragma unroll
    for (int j = 0; j < 32; ++j) buf[wb + j][lane] = silu_f(acc[j]);
    __syncthreads();

    {
        const float* __restrict__ bb = nb2 + wb;
#pragma unroll
        for (int j = 0; j < 32; ++j) acc[j] = bb[j];
    }
    gemm_sgpr(buf, nW2 + wb, lane, acc);
    __syncthreads();
#pragma unroll
    for (int j = 0; j < 32; ++j) buf[wb + j][lane] = silu_f(acc[j]);
    __syncthreads();

    {
        const float* __restrict__ bb = nb3 + wb;
#pragma unroll
        for (int j = 0; j < 32; ++j) acc[j] = bb[j];
    }
    gemm_sgpr(buf, nW3 + wb, lane, acc);

    if (valid) {
        float* hp = &h[(size_t)n * H + wb];
#pragma unroll
        for (int j = 0; j < 32; ++j) hp[j] += acc[j];
    }
}

// ---------------- readout ----------------
__global__ void __launch_bounds__(256, 4)
readout_kernel(const float* __restrict__ h, const float* __restrict__ W_ro,
               const float* __restrict__ b_ro, float* __restrict__ out, int NN)
{
    __shared__ float buf[H][BST];

    const int tid  = threadIdx.x;
    const int lane = tid & 63;
    const int wid  = __builtin_amdgcn_readfirstlane(tid >> 6);
    const int wb   = wid * 32;
    const int n0   = blockIdx.x * 64;

    const int n = n0 + lane;
    const bool valid = (n < NN);
    const int nc = valid ? n : NN - 1;

    stage32(h + (size_t)nc * H + wb, wb, lane, buf);
    __syncthreads();

    float acc[32];
    {
        const float* __restrict__ bb = b_ro + wb;
#pragma unroll
        for (int j = 0; j < 32; ++j) acc[j] = bb[j];
    }
    gemm_sgpr(buf, W_ro + wb, lane, acc);

    float* zn = out + H;
    if (valid) {
        float* zp = &zn[(size_t)n * H + wb];
#pragma unroll
        for (int j = 0; j < 32; ++j) zp[j] = acc[j];
    }

    const float inv = 1.0f / (float)NN;
#pragma unroll
    for (int j = 0; j < 32; ++j) {
        float v = valid ? acc[j] * inv : 0.f;
#pragma unroll
        for (int msk = 1; msk < 64; msk <<= 1)
            v += __shfl_xor(v, msk);
        if (lane == 0) atomicAdd(&out[wb + j], v);
    }
}

extern "C" void kernel_launch(void* const* d_in, const int* in_sizes, int n_in,
                              void* d_out, int out_size, void* d_ws, size_t ws_size,
                              hipStream_t stream) {
    const float* node_pos    = (const float*)d_in[0];
    const float* node_scalar = (const float*)d_in[1];
    const int*   type_ids    = (const int*)d_in[2];
    const int*   edge_index  = (const int*)d_in[3];
    const float* emb         = (const float*)d_in[4];
    const float* W_in        = (const float*)d_in[5];
    const float* b_in        = (const float*)d_in[6];
    const float* eW1 = (const float*)d_in[7];
    const float* eb1 = (const float*)d_in[8];
    const float* eW2 = (const float*)d_in[9];
    const float* eb2 = (const float*)d_in[10];
    const float* eW3 = (const float*)d_in[11];
    const float* eb3 = (const float*)d_in[12];
    const float* cW1 = (const float*)d_in[13];
    const float* cb1 = (const float*)d_in[14];
    const float* cW2 = (const float*)d_in[15];
    const float* cb2 = (const float*)d_in[16];
    const float* nW1 = (const float*)d_in[17];
    const float* nb1 = (const float*)d_in[18];
    const float* nW2 = (const float*)d_in[19];
    const float* nb2 = (const float*)d_in[20];
    const float* nW3 = (const float*)d_in[21];
    const float* nb3 = (const float*)d_in[22];
    const float* W_ro = (const float*)d_in[23];
    const float* b_ro = (const float*)d_in[24];

    const int NN = in_sizes[0] / 3;
    const int E  = in_sizes[3] / 2;
    const int Lc = in_sizes[7] / ((2 * H + 1) * H);
    const int ntypes = in_sizes[4] / 8;

    const int* srcp = edge_index;
    const int* dstp = edge_index + E;

    float* hbuf = (float*)d_out + H;           // h lives in the z_nodes slot

    float* ws     = (float*)d_ws;
    float* m_aggr = ws;                        // NN*H
    float* xb     = ws + (size_t)NN * H;       // NN*3
    float* dxb    = xb + (size_t)NN * 3;       // NN*3

    hipMemcpyAsync(xb, node_pos, sizeof(float) * 3 * (size_t)NN,
                   hipMemcpyDeviceToDevice, stream);
    input_kernel<<<dim3((NN * H + 255) / 256), dim3(256), 0, stream>>>(
        node_scalar, type_ids, emb, W_in, b_in, hbuf, NN, ntypes);

    for (int l = 0; l < Lc; ++l) {
        hipMemsetAsync(m_aggr, 0, sizeof(float) * (size_t)NN * H, stream);
        hipMemsetAsync(dxb, 0, sizeof(float) * (size_t)NN * 3, stream);
        edge_kernel<<<dim3((E + 63) / 64), dim3(256), 0, stream>>>(
            xb, hbuf, srcp, dstp,
            eW1 + (size_t)l * (2 * H + 1) * H, eb1 + (size_t)l * H,
            eW2 + (size_t)l * H * H,           eb2 + (size_t)l * H,
            eW3 + (size_t)l * H * H,           eb3 + (size_t)l * H,
            cW1 + (size_t)l * H * H,           cb1 + (size_t)l * H,
            cW2 + (size_t)l * H,               cb2 + l,
            m_aggr, dxb, E);
        node_kernel<<<dim3((NN + 63) / 64), dim3(256), 0, stream>>>(
            xb, dxb, hbuf, m_aggr,
            nW1 + (size_t)l * 2 * H * H, nb1 + (size_t)l * H,
            nW2 + (size_t)l * H * H,     nb2 + (size_t)l * H,
            nW3 + (size_t)l * H * H,     nb3 + (size_t)l * H, NN);
    }

    hipMemsetAsync(d_out, 0, sizeof(float) * H, stream);
    readout_kernel<<<dim3((NN + 63) / 64), dim3(256), 0, stream>>>(
        hbuf, W_ro, b_ro, (float*)d_out, NN);
}

// Round 4
// 7385.442 us; speedup vs baseline: 1.7217x; 1.7217x over previous
//
#include <hip/hip_runtime.h>
#include <math.h>

#define H 128
#define LDSTR 68   // floats per LDS row; 68*4=272 B, rows 16B-aligned, bank rotation by 4

__device__ __forceinline__ float silu_f(float v) {
    return v / (1.0f + __expf(-v));
}

// acc[j][i] += sum_k buf[k][eb+i] * W[k*H + fb+j], K=128.
// W streamed via VMEM float4 (L1-resident across waves); buf read as broadcast float4.
__device__ __forceinline__ void gemm128(const float (*__restrict__ buf)[LDSTR],
                                        const float* __restrict__ W,
                                        int fb, int eb, float acc[8][4]) {
#pragma unroll 4
    for (int k = 0; k < H; ++k) {
        const float4 a4  = *(const float4*)&buf[k][eb];
        const float4 w04 = *(const float4*)&W[k * H + fb];
        const float4 w14 = *(const float4*)&W[k * H + fb + 4];
        const float av[4] = {a4.x, a4.y, a4.z, a4.w};
        const float wv[8] = {w04.x, w04.y, w04.z, w04.w, w14.x, w14.y, w14.z, w14.w};
#pragma unroll
        for (int j = 0; j < 8; ++j)
#pragma unroll
            for (int i = 0; i < 4; ++i)
                acc[j][i] = fmaf(wv[j], av[i], acc[j][i]);
    }
}

// wave q stages features [q*32, q*32+32) of 64 rows into buf[f][lane] (transposed).
// Global: 8 x float4 gather per lane. LDS: stride-1 lane writes (2-way, free).
__device__ __forceinline__ void stage_rows(const float* __restrict__ rowp, int q, int lane,
                                           float (*__restrict__ buf)[LDSTR]) {
#pragma unroll
    for (int c = 0; c < 8; ++c) {
        const float4 v = *(const float4*)(rowp + 4 * c);
        const int f = q * 32 + 4 * c;
        buf[f + 0][lane] = v.x;
        buf[f + 1][lane] = v.y;
        buf[f + 2][lane] = v.z;
        buf[f + 3][lane] = v.w;
    }
}

__device__ __forceinline__ void prefetch_row(const float* __restrict__ rowp, float4 pre[8]) {
#pragma unroll
    for (int c = 0; c < 8; ++c) pre[c] = *(const float4*)(rowp + 4 * c);
}

__device__ __forceinline__ void store_pre(const float4 pre[8], int q, int lane,
                                          float (*__restrict__ buf)[LDSTR]) {
#pragma unroll
    for (int c = 0; c < 8; ++c) {
        const int f = q * 32 + 4 * c;
        buf[f + 0][lane] = pre[c].x;
        buf[f + 1][lane] = pre[c].y;
        buf[f + 2][lane] = pre[c].z;
        buf[f + 3][lane] = pre[c].w;
    }
}

// ---------------- input embedding + first linear ----------------
__global__ void __launch_bounds__(256)
input_kernel(const float* __restrict__ node_scalar, const int* __restrict__ type_ids,
             const float* __restrict__ emb, const float* __restrict__ W_in,
             const float* __restrict__ b_in, float* __restrict__ hout,
             int NN, int ntypes)
{
    const int idx = blockIdx.x * 256 + threadIdx.x;
    if (idx >= NN * H) return;
    const int n = idx >> 7;
    const int f = idx & (H - 1);
    int t = type_ids[n];
    t = t < 0 ? 0 : (t >= ntypes ? ntypes - 1 : t);
    float s = b_in[f];
#pragma unroll
    for (int k = 0; k < 5; ++k) s = fmaf(node_scalar[n * 5 + k], W_in[k * H + f], s);
#pragma unroll
    for (int k = 0; k < 8; ++k) s = fmaf(emb[t * 8 + k], W_in[(5 + k) * H + f], s);
    hout[idx] = s;
}

// ---------------- per-layer edge kernel ----------------
__global__ void __launch_bounds__(256, 4)
edge_kernel(const float* __restrict__ x, const float* __restrict__ h,
            const int* __restrict__ src, const int* __restrict__ dst,
            const float* __restrict__ eW1, const float* __restrict__ eb1,
            const float* __restrict__ eW2, const float* __restrict__ eb2,
            const float* __restrict__ eW3, const float* __restrict__ eb3,
            const float* __restrict__ cW1, const float* __restrict__ cb1,
            const float* __restrict__ cW2, const float* __restrict__ cb2,
            float* __restrict__ m_aggr, float* __restrict__ dxv,
            int E)
{
    __shared__ float buf[H][LDSTR];          // 34 KB
    __shared__ float d2s[64];
    __shared__ float relx[64], rely[64], relz[64];
    __shared__ int   ssrc[64], sdst[64];
    __shared__ int   evalid[64];

    const int tid  = threadIdx.x;
    const int lane = tid & 63;
    const int q    = tid >> 6;               // wave id: feature slice for staging
    const int e0   = blockIdx.x * 64;

    // geometry: one lane per edge (wave 0)
    if (tid < 64) {
        int e = e0 + tid;
        int v = (e < E) ? 1 : 0;
        if (!v) e = E - 1;
        evalid[tid] = v;
        const int s = src[e], d = dst[e];
        ssrc[tid] = s; sdst[tid] = d;
        const float rx = x[3 * s + 0] - x[3 * d + 0];
        const float ry = x[3 * s + 1] - x[3 * d + 1];
        const float rz = x[3 * s + 2] - x[3 * d + 2];
        relx[tid] = rx; rely[tid] = ry; relz[tid] = rz;
        d2s[tid] = rx * rx + ry * ry + rz * rz;
    }
    __syncthreads();

    // prefetch h[dst] slice into registers (consumed after gemm1 pass 1)
    float4 pre[8];
    prefetch_row(h + (size_t)sdst[lane] * H + q * 32, pre);

    // stage h[src]
    stage_rows(h + (size_t)ssrc[lane] * H + q * 32, q, lane, buf);
    __syncthreads();

    const int fg = tid & 15, eg = tid >> 4;
    const int fb = fg * 8, eb = eg * 4;

    float acc[8][4];
    {
#pragma unroll
        for (int j = 0; j < 8; ++j) {
            const float bv   = eb1[fb + j];
            const float w256 = eW1[(size_t)256 * H + fb + j];
#pragma unroll
            for (int i = 0; i < 4; ++i)
                acc[j][i] = fmaf(d2s[eb + i], w256, bv);
        }
    }
    gemm128(buf, eW1, fb, eb, acc);                      // k = 0..127  (h_src)
    __syncthreads();
    store_pre(pre, q, lane, buf);                        // h_dst from regs
    __syncthreads();
    gemm128(buf, eW1 + (size_t)128 * H, fb, eb, acc);    // k = 128..255 (h_dst)
    __syncthreads();

#pragma unroll
    for (int j = 0; j < 8; ++j)
#pragma unroll
        for (int i = 0; i < 4; ++i)
            buf[fb + j][eb + i] = silu_f(acc[j][i]);     // m1
    __syncthreads();

#pragma unroll
    for (int j = 0; j < 8; ++j) {
        const float bv = eb2[fb + j];
#pragma unroll
        for (int i = 0; i < 4; ++i) acc[j][i] = bv;
    }
    gemm128(buf, eW2, fb, eb, acc);
    __syncthreads();
#pragma unroll
    for (int j = 0; j < 8; ++j)
#pragma unroll
        for (int i = 0; i < 4; ++i)
            buf[fb + j][eb + i] = silu_f(acc[j][i]);     // m2
    __syncthreads();

#pragma unroll
    for (int j = 0; j < 8; ++j) {
        const float bv = eb3[fb + j];
#pragma unroll
        for (int i = 0; i < 4; ++i) acc[j][i] = bv;
    }
    gemm128(buf, eW3, fb, eb, acc);                      // m

    // scatter m into m_aggr[src]
#pragma unroll
    for (int i = 0; i < 4; ++i) {
        const int e = eb + i;
        if (evalid[e]) {
            float* dp = &m_aggr[(size_t)ssrc[e] * H + fb];
#pragma unroll
            for (int j = 0; j < 8; ++j) atomicAdd(dp + j, acc[j][i]);
        }
    }
    __syncthreads();
#pragma unroll
    for (int j = 0; j < 8; ++j)
#pragma unroll
        for (int i = 0; i < 4; ++i)
            buf[fb + j][eb + i] = acc[j][i];             // stash m
    __syncthreads();

    // coord MLP
#pragma unroll
    for (int j = 0; j < 8; ++j) {
        const float bv = cb1[fb + j];
#pragma unroll
        for (int i = 0; i < 4; ++i) acc[j][i] = bv;
    }
    gemm128(buf, cW1, fb, eb, acc);

    float c2[8];
#pragma unroll
    for (int j = 0; j < 8; ++j) c2[j] = cW2[fb + j];

    float part[4];
#pragma unroll
    for (int i = 0; i < 4; ++i) {
        float s = 0.f;
#pragma unroll
        for (int j = 0; j < 8; ++j) s = fmaf(silu_f(acc[j][i]), c2[j], s);
        part[i] = s;
    }
#pragma unroll
    for (int i = 0; i < 4; ++i) {
#pragma unroll
        for (int msk = 1; msk < 16; msk <<= 1)
            part[i] += __shfl_xor(part[i], msk);
    }
    if (fg == 0) {
        const float cb2v = cb2[0];
#pragma unroll
        for (int i = 0; i < 4; ++i) {
            const int e = eb + i;
            if (evalid[e]) {
                const float coef = tanhf(part[i] + cb2v);
                float* dp = &dxv[(size_t)ssrc[e] * 3];
                atomicAdd(dp + 0, relx[e] * coef);
                atomicAdd(dp + 1, rely[e] * coef);
                atomicAdd(dp + 2, relz[e] * coef);
            }
        }
    }
}

// ---------------- per-layer node kernel ----------------
__global__ void __launch_bounds__(256, 4)
node_kernel(float* __restrict__ x, const float* __restrict__ dxv,
            float* __restrict__ h, const float* __restrict__ m_aggr,
            const float* __restrict__ nW1, const float* __restrict__ nb1,
            const float* __restrict__ nW2, const float* __restrict__ nb2,
            const float* __restrict__ nW3, const float* __restrict__ nb3,
            int NN)
{
    __shared__ float buf[H][LDSTR];

    const int tid  = threadIdx.x;
    const int lane = tid & 63;
    const int q    = tid >> 6;
    const int n0   = blockIdx.x * 64;

    const int nl = n0 + lane;
    const int nc = (nl < NN) ? nl : NN - 1;

    if (tid < 192) {
        const int nn = n0 + tid / 3;
        if (nn < NN) {
            const int c = tid % 3;
            x[(size_t)nn * 3 + c] += dxv[(size_t)nn * 3 + c];
        }
    }

    float4 pre[8];
    prefetch_row(m_aggr + (size_t)nc * H + q * 32, pre);
    stage_rows(h + (size_t)nc * H + q * 32, q, lane, buf);
    __syncthreads();

    const int fg = tid & 15, eg = tid >> 4;
    const int fb = fg * 8, eb = eg * 4;
    float acc[8][4];

#pragma unroll
    for (int j = 0; j < 8; ++j) {
        const float bv = nb1[fb + j];
#pragma unroll
        for (int i = 0; i < 4; ++i) acc[j][i] = bv;
    }
    gemm128(buf, nW1, fb, eb, acc);                      // k = 0..127 (h)
    __syncthreads();
    store_pre(pre, q, lane, buf);                        // m_aggr
    __syncthreads();
    gemm128(buf, nW1 + (size_t)128 * H, fb, eb, acc);    // k = 128..255
    __syncthreads();

#pragma unroll
    for (int j = 0; j < 8; ++j)
#pragma unroll
        for (int i = 0; i < 4; ++i)
            buf[fb + j][eb + i] = silu_f(acc[j][i]);
    __syncthreads();

#pragma unroll
    for (int j = 0; j < 8; ++j) {
        const float bv = nb2[fb + j];
#pragma unroll
        for (int i = 0; i < 4; ++i) acc[j][i] = bv;
    }
    gemm128(buf, nW2, fb, eb, acc);
    __syncthreads();
#pragma unroll
    for (int j = 0; j < 8; ++j)
#pragma unroll
        for (int i = 0; i < 4; ++i)
            buf[fb + j][eb + i] = silu_f(acc[j][i]);
    __syncthreads();

#pragma unroll
    for (int j = 0; j < 8; ++j) {
        const float bv = nb3[fb + j];
#pragma unroll
        for (int i = 0; i < 4; ++i) acc[j][i] = bv;
    }
    gemm128(buf, nW3, fb, eb, acc);

#pragma unroll
    for (int i = 0; i < 4; ++i) {
        const int n = n0 + eb + i;
        if (n < NN) {
            float* hp = &h[(size_t)n * H + fb];
#pragma unroll
            for (int j = 0; j < 8; ++j) hp[j] += acc[j][i];
        }
    }
}

// ---------------- readout ----------------
__global__ void __launch_bounds__(256, 4)
readout_kernel(const float* __restrict__ h, const float* __restrict__ W_ro,
               const float* __restrict__ b_ro, float* __restrict__ out, int NN)
{
    __shared__ float buf[H][LDSTR];
    __shared__ float sred[4][H];

    const int tid  = threadIdx.x;
    const int lane = tid & 63;
    const int q    = tid >> 6;
    const int n0   = blockIdx.x * 64;

    const int nl = n0 + lane;
    const int nc = (nl < NN) ? nl : NN - 1;

    stage_rows(h + (size_t)nc * H + q * 32, q, lane, buf);
    __syncthreads();

    const int fg = tid & 15, eg = tid >> 4;
    const int fb = fg * 8, eb = eg * 4;
    float acc[8][4];
#pragma unroll
    for (int j = 0; j < 8; ++j) {
        const float bv = b_ro[fb + j];
#pragma unroll
        for (int i = 0; i < 4; ++i) acc[j][i] = bv;
    }
    gemm128(buf, W_ro, fb, eb, acc);

    float* zn = out + H;
    const float inv = 1.0f / (float)NN;
    float s[8];
#pragma unroll
    for (int j = 0; j < 8; ++j) s[j] = 0.f;
#pragma unroll
    for (int i = 0; i < 4; ++i) {
        const int n = n0 + eb + i;
        if (n < NN) {
            float* zp = &zn[(size_t)n * H + fb];
#pragma unroll
            for (int j = 0; j < 8; ++j) { zp[j] = acc[j][i]; s[j] += acc[j][i]; }
        }
    }
    // reduce over edges: across eg groups within the wave (masks 16, 32)
#pragma unroll
    for (int j = 0; j < 8; ++j) {
        s[j] += __shfl_xor(s[j], 16);
        s[j] += __shfl_xor(s[j], 32);
    }
    if ((lane >> 4) == 0) {   // one 16-lane group per wave holds full wave sums
#pragma unroll
        for (int j = 0; j < 8; ++j) sred[q][fb + j] = s[j] * inv;
    }
    __syncthreads();
    if (tid < H) {
        const float v = sred[0][tid] + sred[1][tid] + sred[2][tid] + sred[3][tid];
        atomicAdd(&out[tid], v);
    }
}

extern "C" void kernel_launch(void* const* d_in, const int* in_sizes, int n_in,
                              void* d_out, int out_size, void* d_ws, size_t ws_size,
                              hipStream_t stream) {
    const float* node_pos    = (const float*)d_in[0];
    const float* node_scalar = (const float*)d_in[1];
    const int*   type_ids    = (const int*)d_in[2];
    const int*   edge_index  = (const int*)d_in[3];
    const float* emb         = (const float*)d_in[4];
    const float* W_in        = (const float*)d_in[5];
    const float* b_in        = (const float*)d_in[6];
    const float* eW1 = (const float*)d_in[7];
    const float* eb1 = (const float*)d_in[8];
    const float* eW2 = (const float*)d_in[9];
    const float* eb2 = (const float*)d_in[10];
    const float* eW3 = (const float*)d_in[11];
    const float* eb3 = (const float*)d_in[12];
    const float* cW1 = (const float*)d_in[13];
    const float* cb1 = (const float*)d_in[14];
    const float* cW2 = (const float*)d_in[15];
    const float* cb2 = (const float*)d_in[16];
    const float* nW1 = (const float*)d_in[17];
    const float* nb1 = (const float*)d_in[18];
    const float* nW2 = (const float*)d_in[19];
    const float* nb2 = (const float*)d_in[20];
    const float* nW3 = (const float*)d_in[21];
    const float* nb3 = (const float*)d_in[22];
    const float* W_ro = (const float*)d_in[23];
    const float* b_ro = (const float*)d_in[24];

    const int NN = in_sizes[0] / 3;
    const int E  = in_sizes[3] / 2;
    const int Lc = in_sizes[7] / ((2 * H + 1) * H);
    const int ntypes = in_sizes[4] / 8;

    const int* srcp = edge_index;
    const int* dstp = edge_index + E;

    float* hbuf = (float*)d_out + H;           // h lives in the z_nodes slot

    float* ws     = (float*)d_ws;
    float* m_aggr = ws;                        // NN*H
    float* xb     = ws + (size_t)NN * H;       // NN*3
    float* dxb    = xb + (size_t)NN * 3;       // NN*3

    hipMemcpyAsync(xb, node_pos, sizeof(float) * 3 * (size_t)NN,
                   hipMemcpyDeviceToDevice, stream);
    input_kernel<<<dim3((NN * H + 255) / 256), dim3(256), 0, stream>>>(
        node_scalar, type_ids, emb, W_in, b_in, hbuf, NN, ntypes);

    for (int l = 0; l < Lc; ++l) {
        hipMemsetAsync(m_aggr, 0, sizeof(float) * (size_t)NN * H, stream);
        hipMemsetAsync(dxb, 0, sizeof(float) * (size_t)NN * 3, stream);
        edge_kernel<<<dim3((E + 63) / 64), dim3(256), 0, stream>>>(
            xb, hbuf, srcp, dstp,
            eW1 + (size_t)l * (2 * H + 1) * H, eb1 + (size_t)l * H,
            eW2 + (size_t)l * H * H,           eb2 + (size_t)l * H,
            eW3 + (size_t)l * H * H,           eb3 + (size_t)l * H,
            cW1 + (size_t)l * H * H,           cb1 + (size_t)l * H,
            cW2 + (size_t)l * H,               cb2 + l,
            m_aggr, dxb, E);
        node_kernel<<<dim3((NN + 63) / 64), dim3(256), 0, stream>>>(
            xb, dxb, hbuf, m_aggr,
            nW1 + (size_t)l * 2 * H * H, nb1 + (size_t)l * H,
            nW2 + (size_t)l * H * H,     nb2 + (size_t)l * H,
            nW3 + (size_t)l * H * H,     nb3 + (size_t)l * H, NN);
    }

    hipMemsetAsync(d_out, 0, sizeof(float) * H, stream);
    readout_kernel<<<dim3((NN + 63) / 64), dim3(256), 0, stream>>>(
        hbuf, W_ro, b_ro, (float*)d_out, NN);
}

// Round 5
// 4110.419 us; speedup vs baseline: 3.0935x; 1.7968x over previous
//
#include <hip/hip_runtime.h>
#include <math.h>

#define H 128
#define LDSTR 68   // floats per LDS row; 68*4=272 B, rows 16B-aligned

__device__ __forceinline__ float silu_f(float v) {
    return v / (1.0f + __expf(-v));
}

// Wave-cooperative GEMM tile: lane owns features {f2, f2+1}, edges [ew, ew+16).
// Per k: weight = float2 per lane (512 B/wave coalesced, no redundancy);
// activations = 4x ds_read_b128, all lanes same address (broadcast, conflict-free).
__device__ __forceinline__ void gemm_b(const float (*__restrict__ buf)[LDSTR],
                                       const float* __restrict__ W,
                                       int f2, int ew,
                                       float acc0[16], float acc1[16]) {
#pragma unroll 4
    for (int k = 0; k < H; ++k) {
        const float2 w  = *(const float2*)&W[(size_t)k * H + f2];
        const float4 a0 = *(const float4*)&buf[k][ew + 0];
        const float4 a1 = *(const float4*)&buf[k][ew + 4];
        const float4 a2 = *(const float4*)&buf[k][ew + 8];
        const float4 a3 = *(const float4*)&buf[k][ew + 12];
        const float av[16] = {a0.x, a0.y, a0.z, a0.w, a1.x, a1.y, a1.z, a1.w,
                              a2.x, a2.y, a2.z, a2.w, a3.x, a3.y, a3.z, a3.w};
#pragma unroll
        for (int i = 0; i < 16; ++i) {
            acc0[i] = fmaf(w.x, av[i], acc0[i]);
            acc1[i] = fmaf(w.y, av[i], acc1[i]);
        }
    }
}

// lane writes its 2 feature-rows x 16 edge-cols back to buf (optionally silu)
template <bool DO_SILU>
__device__ __forceinline__ void writeback(float (*__restrict__ buf)[LDSTR],
                                          int f2, int ew,
                                          const float acc0[16], const float acc1[16]) {
#pragma unroll
    for (int t = 0; t < 4; ++t) {
        float4 v0, v1;
        v0.x = acc0[4 * t + 0]; v0.y = acc0[4 * t + 1]; v0.z = acc0[4 * t + 2]; v0.w = acc0[4 * t + 3];
        v1.x = acc1[4 * t + 0]; v1.y = acc1[4 * t + 1]; v1.z = acc1[4 * t + 2]; v1.w = acc1[4 * t + 3];
        if (DO_SILU) {
            v0.x = silu_f(v0.x); v0.y = silu_f(v0.y); v0.z = silu_f(v0.z); v0.w = silu_f(v0.w);
            v1.x = silu_f(v1.x); v1.y = silu_f(v1.y); v1.z = silu_f(v1.z); v1.w = silu_f(v1.w);
        }
        *(float4*)&buf[f2 + 0][ew + 4 * t] = v0;
        *(float4*)&buf[f2 + 1][ew + 4 * t] = v1;
    }
}

// wave q stages features [q*32, q*32+32) of 64 rows into buf[f][lane] (transposed)
__device__ __forceinline__ void stage_rows(const float* __restrict__ rowp, int q, int lane,
                                           float (*__restrict__ buf)[LDSTR]) {
#pragma unroll
    for (int c = 0; c < 8; ++c) {
        const float4 v = *(const float4*)(rowp + 4 * c);
        const int f = q * 32 + 4 * c;
        buf[f + 0][lane] = v.x;
        buf[f + 1][lane] = v.y;
        buf[f + 2][lane] = v.z;
        buf[f + 3][lane] = v.w;
    }
}

__device__ __forceinline__ void prefetch_row(const float* __restrict__ rowp, float4 pre[8]) {
#pragma unroll
    for (int c = 0; c < 8; ++c) pre[c] = *(const float4*)(rowp + 4 * c);
}

__device__ __forceinline__ void store_pre(const float4 pre[8], int q, int lane,
                                          float (*__restrict__ buf)[LDSTR]) {
#pragma unroll
    for (int c = 0; c < 8; ++c) {
        const int f = q * 32 + 4 * c;
        buf[f + 0][lane] = pre[c].x;
        buf[f + 1][lane] = pre[c].y;
        buf[f + 2][lane] = pre[c].z;
        buf[f + 3][lane] = pre[c].w;
    }
}

// ---------------- input embedding + first linear ----------------
__global__ void __launch_bounds__(256)
input_kernel(const float* __restrict__ node_scalar, const int* __restrict__ type_ids,
             const float* __restrict__ emb, const float* __restrict__ W_in,
             const float* __restrict__ b_in, float* __restrict__ hout,
             int NN, int ntypes)
{
    const int idx = blockIdx.x * 256 + threadIdx.x;
    if (idx >= NN * H) return;
    const int n = idx >> 7;
    const int f = idx & (H - 1);
    int t = type_ids[n];
    t = t < 0 ? 0 : (t >= ntypes ? ntypes - 1 : t);
    float s = b_in[f];
#pragma unroll
    for (int k = 0; k < 5; ++k) s = fmaf(node_scalar[n * 5 + k], W_in[k * H + f], s);
#pragma unroll
    for (int k = 0; k < 8; ++k) s = fmaf(emb[t * 8 + k], W_in[(5 + k) * H + f], s);
    hout[idx] = s;
}

// ---------------- per-layer edge kernel ----------------
__global__ void __launch_bounds__(256, 4)
edge_kernel(const float* __restrict__ x, const float* __restrict__ h,
            const int* __restrict__ src, const int* __restrict__ dst,
            const float* __restrict__ eW1, const float* __restrict__ eb1,
            const float* __restrict__ eW2, const float* __restrict__ eb2,
            const float* __restrict__ eW3, const float* __restrict__ eb3,
            const float* __restrict__ cW1, const float* __restrict__ cb1,
            const float* __restrict__ cW2, const float* __restrict__ cb2,
            float* __restrict__ m_aggr, float* __restrict__ dxv,
            int E)
{
    __shared__ float buf[H][LDSTR];          // 34 KB
    __shared__ float d2s[64];
    __shared__ float relx[64], rely[64], relz[64];
    __shared__ int   ssrc[64], sdst[64];
    __shared__ int   evalid[64];

    const int tid  = threadIdx.x;
    const int lane = tid & 63;
    const int q    = tid >> 6;               // wave id
    const int f2   = lane * 2;               // this lane's 2 features
    const int ew   = q * 16;                 // this wave's 16 edges
    const int e0   = blockIdx.x * 64;

    if (tid < 64) {
        int e = e0 + tid;
        int v = (e < E) ? 1 : 0;
        if (!v) e = E - 1;
        evalid[tid] = v;
        const int s = src[e], d = dst[e];
        ssrc[tid] = s; sdst[tid] = d;
        const float rx = x[3 * s + 0] - x[3 * d + 0];
        const float ry = x[3 * s + 1] - x[3 * d + 1];
        const float rz = x[3 * s + 2] - x[3 * d + 2];
        relx[tid] = rx; rely[tid] = ry; relz[tid] = rz;
        d2s[tid] = rx * rx + ry * ry + rz * rz;
    }
    __syncthreads();

    // prefetch h[dst] slice (pass-2 operand of gemm1), stage h[src]
    float4 pre[8];
    prefetch_row(h + (size_t)sdst[lane] * H + q * 32, pre);
    stage_rows(h + (size_t)ssrc[lane] * H + q * 32, q, lane, buf);
    __syncthreads();

    float acc0[16], acc1[16];
    {
        const float2 bv = *(const float2*)&eb1[f2];
        const float2 wd = *(const float2*)&eW1[(size_t)256 * H + f2];
#pragma unroll
        for (int i = 0; i < 16; ++i) {
            const float d2 = d2s[ew + i];
            acc0[i] = fmaf(d2, wd.x, bv.x);
            acc1[i] = fmaf(d2, wd.y, bv.y);
        }
    }
    gemm_b(buf, eW1, f2, ew, acc0, acc1);                    // k = 0..127 (h_src)
    __syncthreads();
    store_pre(pre, q, lane, buf);                            // h_dst
    __syncthreads();
    gemm_b(buf, eW1 + (size_t)128 * H, f2, ew, acc0, acc1);  // k = 128..255 (h_dst)
    __syncthreads();

    writeback<true>(buf, f2, ew, acc0, acc1);                // m1
    __syncthreads();

    {
        const float2 bv = *(const float2*)&eb2[f2];
#pragma unroll
        for (int i = 0; i < 16; ++i) { acc0[i] = bv.x; acc1[i] = bv.y; }
    }
    gemm_b(buf, eW2, f2, ew, acc0, acc1);
    __syncthreads();
    writeback<true>(buf, f2, ew, acc0, acc1);                // m2
    __syncthreads();

    {
        const float2 bv = *(const float2*)&eb3[f2];
#pragma unroll
        for (int i = 0; i < 16; ++i) { acc0[i] = bv.x; acc1[i] = bv.y; }
    }
    gemm_b(buf, eW3, f2, ew, acc0, acc1);                    // m

    // scatter m into m_aggr[src]: per edge, wave covers 128 contiguous floats
#pragma unroll
    for (int i = 0; i < 16; ++i) {
        const int e = ew + i;
        if (evalid[e]) {
            float* dp = &m_aggr[(size_t)ssrc[e] * H + f2];
            atomicAdd(dp + 0, acc0[i]);
            atomicAdd(dp + 1, acc1[i]);
        }
    }
    __syncthreads();
    writeback<false>(buf, f2, ew, acc0, acc1);               // stash m
    __syncthreads();

    // coord MLP
    {
        const float2 bv = *(const float2*)&cb1[f2];
#pragma unroll
        for (int i = 0; i < 16; ++i) { acc0[i] = bv.x; acc1[i] = bv.y; }
    }
    gemm_b(buf, cW1, f2, ew, acc0, acc1);

    {
        const float2 c2 = *(const float2*)&cW2[f2];
        float p[16];
#pragma unroll
        for (int i = 0; i < 16; ++i)
            p[i] = fmaf(silu_f(acc0[i]), c2.x, silu_f(acc1[i]) * c2.y);
        // full-wave butterfly: all lanes end with the 128-feature sum per edge
#pragma unroll
        for (int msk = 1; msk < 64; msk <<= 1)
#pragma unroll
            for (int i = 0; i < 16; ++i)
                p[i] += __shfl_xor(p[i], msk);
        // compile-time select (no runtime register indexing)
        float myp = 0.f;
#pragma unroll
        for (int i = 0; i < 16; ++i) myp = (lane == i) ? p[i] : myp;
        if (lane < 16) {
            const int e = ew + lane;
            if (evalid[e]) {
                const float coef = tanhf(myp + cb2[0]);
                float* dp = &dxv[(size_t)ssrc[e] * 3];
                atomicAdd(dp + 0, relx[e] * coef);
                atomicAdd(dp + 1, rely[e] * coef);
                atomicAdd(dp + 2, relz[e] * coef);
            }
        }
    }
}

// ---------------- per-layer node kernel ----------------
__global__ void __launch_bounds__(256, 4)
node_kernel(float* __restrict__ x, const float* __restrict__ dxv,
            float* __restrict__ h, const float* __restrict__ m_aggr,
            const float* __restrict__ nW1, const float* __restrict__ nb1,
            const float* __restrict__ nW2, const float* __restrict__ nb2,
            const float* __restrict__ nW3, const float* __restrict__ nb3,
            int NN)
{
    __shared__ float buf[H][LDSTR];

    const int tid  = threadIdx.x;
    const int lane = tid & 63;
    const int q    = tid >> 6;
    const int f2   = lane * 2;
    const int ew   = q * 16;
    const int n0   = blockIdx.x * 64;

    const int nl = n0 + lane;
    const int nc = (nl < NN) ? nl : NN - 1;

    if (tid < 192) {
        const int nn = n0 + tid / 3;
        if (nn < NN) {
            const int c = tid % 3;
            x[(size_t)nn * 3 + c] += dxv[(size_t)nn * 3 + c];
        }
    }

    float4 pre[8];
    prefetch_row(m_aggr + (size_t)nc * H + q * 32, pre);
    stage_rows(h + (size_t)nc * H + q * 32, q, lane, buf);
    __syncthreads();

    float acc0[16], acc1[16];
    {
        const float2 bv = *(const float2*)&nb1[f2];
#pragma unroll
        for (int i = 0; i < 16; ++i) { acc0[i] = bv.x; acc1[i] = bv.y; }
    }
    gemm_b(buf, nW1, f2, ew, acc0, acc1);                    // k = 0..127 (h)
    __syncthreads();
    store_pre(pre, q, lane, buf);                            // m_aggr
    __syncthreads();
    gemm_b(buf, nW1 + (size_t)128 * H, f2, ew, acc0, acc1);  // k = 128..255
    __syncthreads();

    writeback<true>(buf, f2, ew, acc0, acc1);
    __syncthreads();

    {
        const float2 bv = *(const float2*)&nb2[f2];
#pragma unroll
        for (int i = 0; i < 16; ++i) { acc0[i] = bv.x; acc1[i] = bv.y; }
    }
    gemm_b(buf, nW2, f2, ew, acc0, acc1);
    __syncthreads();
    writeback<true>(buf, f2, ew, acc0, acc1);
    __syncthreads();

    {
        const float2 bv = *(const float2*)&nb3[f2];
#pragma unroll
        for (int i = 0; i < 16; ++i) { acc0[i] = bv.x; acc1[i] = bv.y; }
    }
    gemm_b(buf, nW3, f2, ew, acc0, acc1);

#pragma unroll
    for (int i = 0; i < 16; ++i) {
        const int n = n0 + ew + i;
        if (n < NN) {
            float2* hp = (float2*)&h[(size_t)n * H + f2];
            float2 v = *hp;
            v.x += acc0[i]; v.y += acc1[i];
            *hp = v;
        }
    }
}

// ---------------- readout ----------------
__global__ void __launch_bounds__(256, 4)
readout_kernel(const float* __restrict__ h, const float* __restrict__ W_ro,
               const float* __restrict__ b_ro, float* __restrict__ out, int NN)
{
    __shared__ float buf[H][LDSTR];
    __shared__ float sred[4][H];

    const int tid  = threadIdx.x;
    const int lane = tid & 63;
    const int q    = tid >> 6;
    const int f2   = lane * 2;
    const int ew   = q * 16;
    const int n0   = blockIdx.x * 64;

    const int nl = n0 + lane;
    const int nc = (nl < NN) ? nl : NN - 1;

    stage_rows(h + (size_t)nc * H + q * 32, q, lane, buf);
    __syncthreads();

    float acc0[16], acc1[16];
    {
        const float2 bv = *(const float2*)&b_ro[f2];
#pragma unroll
        for (int i = 0; i < 16; ++i) { acc0[i] = bv.x; acc1[i] = bv.y; }
    }
    gemm_b(buf, W_ro, f2, ew, acc0, acc1);

    float* zn = out + H;
    float s0 = 0.f, s1 = 0.f;
#pragma unroll
    for (int i = 0; i < 16; ++i) {
        const int n = n0 + ew + i;
        if (n < NN) {
            float2* zp = (float2*)&zn[(size_t)n * H + f2];
            float2 v; v.x = acc0[i]; v.y = acc1[i];
            *zp = v;
            s0 += acc0[i]; s1 += acc1[i];
        }
    }
    sred[q][f2 + 0] = s0;
    sred[q][f2 + 1] = s1;
    __syncthreads();
    if (tid < H) {
        const float inv = 1.0f / (float)NN;
        const float v = (sred[0][tid] + sred[1][tid] + sred[2][tid] + sred[3][tid]) * inv;
        atomicAdd(&out[tid], v);
    }
}

extern "C" void kernel_launch(void* const* d_in, const int* in_sizes, int n_in,
                              void* d_out, int out_size, void* d_ws, size_t ws_size,
                              hipStream_t stream) {
    const float* node_pos    = (const float*)d_in[0];
    const float* node_scalar = (const float*)d_in[1];
    const int*   type_ids    = (const int*)d_in[2];
    const int*   edge_index  = (const int*)d_in[3];
    const float* emb         = (const float*)d_in[4];
    const float* W_in        = (const float*)d_in[5];
    const float* b_in        = (const float*)d_in[6];
    const float* eW1 = (const float*)d_in[7];
    const float* eb1 = (const float*)d_in[8];
    const float* eW2 = (const float*)d_in[9];
    const float* eb2 = (const float*)d_in[10];
    const float* eW3 = (const float*)d_in[11];
    const float* eb3 = (const float*)d_in[12];
    const float* cW1 = (const float*)d_in[13];
    const float* cb1 = (const float*)d_in[14];
    const float* cW2 = (const float*)d_in[15];
    const float* cb2 = (const float*)d_in[16];
    const float* nW1 = (const float*)d_in[17];
    const float* nb1 = (const float*)d_in[18];
    const float* nW2 = (const float*)d_in[19];
    const float* nb2 = (const float*)d_in[20];
    const float* nW3 = (const float*)d_in[21];
    const float* nb3 = (const float*)d_in[22];
    const float* W_ro = (const float*)d_in[23];
    const float* b_ro = (const float*)d_in[24];

    const int NN = in_sizes[0] / 3;
    const int E  = in_sizes[3] / 2;
    const int Lc = in_sizes[7] / ((2 * H + 1) * H);
    const int ntypes = in_sizes[4] / 8;

    const int* srcp = edge_index;
    const int* dstp = edge_index + E;

    float* hbuf = (float*)d_out + H;           // h lives in the z_nodes slot

    float* ws     = (float*)d_ws;
    float* m_aggr = ws;                        // NN*H
    float* xb     = ws + (size_t)NN * H;       // NN*3
    float* dxb    = xb + (size_t)NN * 3;       // NN*3

    hipMemcpyAsync(xb, node_pos, sizeof(float) * 3 * (size_t)NN,
                   hipMemcpyDeviceToDevice, stream);
    input_kernel<<<dim3((NN * H + 255) / 256), dim3(256), 0, stream>>>(
        node_scalar, type_ids, emb, W_in, b_in, hbuf, NN, ntypes);

    for (int l = 0; l < Lc; ++l) {
        hipMemsetAsync(m_aggr, 0, sizeof(float) * (size_t)NN * H, stream);
        hipMemsetAsync(dxb, 0, sizeof(float) * (size_t)NN * 3, stream);
        edge_kernel<<<dim3((E + 63) / 64), dim3(256), 0, stream>>>(
            xb, hbuf, srcp, dstp,
            eW1 + (size_t)l * (2 * H + 1) * H, eb1 + (size_t)l * H,
            eW2 + (size_t)l * H * H,           eb2 + (size_t)l * H,
            eW3 + (size_t)l * H * H,           eb3 + (size_t)l * H,
            cW1 + (size_t)l * H * H,           cb1 + (size_t)l * H,
            cW2 + (size_t)l * H,               cb2 + l,
            m_aggr, dxb, E);
        node_kernel<<<dim3((NN + 63) / 64), dim3(256), 0, stream>>>(
            xb, dxb, hbuf, m_aggr,
            nW1 + (size_t)l * 2 * H * H, nb1 + (size_t)l * H,
            nW2 + (size_t)l * H * H,     nb2 + (size_t)l * H,
            nW3 + (size_t)l * H * H,     nb3 + (size_t)l * H, NN);
    }

    hipMemsetAsync(d_out, 0, sizeof(float) * H, stream);
    readout_kernel<<<dim3((NN + 63) / 64), dim3(256), 0, stream>>>(
        hbuf, W_ro, b_ro, (float*)d_out, NN);
}

// Round 7
// 3352.645 us; speedup vs baseline: 3.7926x; 1.2260x over previous
//
#include <hip/hip_runtime.h>
#include <math.h>

#define H 128
#define LDSTR 68   // floats per LDS row; 68*4=272 B, rows 16B-aligned

__device__ __forceinline__ float silu_f(float v) {
    return v / (1.0f + __expf(-v));
}

// Wave-cooperative GEMM tile: lane owns features {f2, f2+1}, edges [ew, ew+16).
// Per k: weight = float2 per lane (512 B/wave coalesced, no redundancy);
// activations = 4x ds_read_b128, all lanes same address (broadcast, conflict-free).
__device__ __forceinline__ void gemm_b(const float (*__restrict__ buf)[LDSTR],
                                       const float* __restrict__ W,
                                       int f2, int ew,
                                       float acc0[16], float acc1[16]) {
#pragma unroll 4
    for (int k = 0; k < H; ++k) {
        const float2 w  = *(const float2*)&W[(size_t)k * H + f2];
        const float4 a0 = *(const float4*)&buf[k][ew + 0];
        const float4 a1 = *(const float4*)&buf[k][ew + 4];
        const float4 a2 = *(const float4*)&buf[k][ew + 8];
        const float4 a3 = *(const float4*)&buf[k][ew + 12];
        const float av[16] = {a0.x, a0.y, a0.z, a0.w, a1.x, a1.y, a1.z, a1.w,
                              a2.x, a2.y, a2.z, a2.w, a3.x, a3.y, a3.z, a3.w};
#pragma unroll
        for (int i = 0; i < 16; ++i) {
            acc0[i] = fmaf(w.x, av[i], acc0[i]);
            acc1[i] = fmaf(w.y, av[i], acc1[i]);
        }
    }
}

template <bool DO_SILU>
__device__ __forceinline__ void writeback(float (*__restrict__ buf)[LDSTR],
                                          int f2, int ew,
                                          const float acc0[16], const float acc1[16]) {
#pragma unroll
    for (int t = 0; t < 4; ++t) {
        float4 v0, v1;
        v0.x = acc0[4 * t + 0]; v0.y = acc0[4 * t + 1]; v0.z = acc0[4 * t + 2]; v0.w = acc0[4 * t + 3];
        v1.x = acc1[4 * t + 0]; v1.y = acc1[4 * t + 1]; v1.z = acc1[4 * t + 2]; v1.w = acc1[4 * t + 3];
        if (DO_SILU) {
            v0.x = silu_f(v0.x); v0.y = silu_f(v0.y); v0.z = silu_f(v0.z); v0.w = silu_f(v0.w);
            v1.x = silu_f(v1.x); v1.y = silu_f(v1.y); v1.z = silu_f(v1.z); v1.w = silu_f(v1.w);
        }
        *(float4*)&buf[f2 + 0][ew + 4 * t] = v0;
        *(float4*)&buf[f2 + 1][ew + 4 * t] = v1;
    }
}

__device__ __forceinline__ void stage_rows(const float* __restrict__ rowp, int q, int lane,
                                           float (*__restrict__ buf)[LDSTR]) {
#pragma unroll
    for (int c = 0; c < 8; ++c) {
        const float4 v = *(const float4*)(rowp + 4 * c);
        const int f = q * 32 + 4 * c;
        buf[f + 0][lane] = v.x;
        buf[f + 1][lane] = v.y;
        buf[f + 2][lane] = v.z;
        buf[f + 3][lane] = v.w;
    }
}

__device__ __forceinline__ void prefetch_row(const float* __restrict__ rowp, float4 pre[8]) {
#pragma unroll
    for (int c = 0; c < 8; ++c) pre[c] = *(const float4*)(rowp + 4 * c);
}

__device__ __forceinline__ void store_pre(const float4 pre[8], int q, int lane,
                                          float (*__restrict__ buf)[LDSTR]) {
#pragma unroll
    for (int c = 0; c < 8; ++c) {
        const int f = q * 32 + 4 * c;
        buf[f + 0][lane] = pre[c].x;
        buf[f + 1][lane] = pre[c].y;
        buf[f + 2][lane] = pre[c].z;
        buf[f + 3][lane] = pre[c].w;
    }
}

// ---------------- input embedding + first linear ----------------
__global__ void __launch_bounds__(256)
input_kernel(const float* __restrict__ node_scalar, const int* __restrict__ type_ids,
             const float* __restrict__ emb, const float* __restrict__ W_in,
             const float* __restrict__ b_in, float* __restrict__ hout,
             int NN, int ntypes)
{
    const int idx = blockIdx.x * 256 + threadIdx.x;
    if (idx >= NN * H) return;
    const int n = idx >> 7;
    const int f = idx & (H - 1);
    int t = type_ids[n];
    t = t < 0 ? 0 : (t >= ntypes ? ntypes - 1 : t);
    float s = b_in[f];
#pragma unroll
    for (int k = 0; k < 5; ++k) s = fmaf(node_scalar[n * 5 + k], W_in[k * H + f], s);
#pragma unroll
    for (int k = 0; k < 8; ++k) s = fmaf(emb[t * 8 + k], W_in[(5 + k) * H + f], s);
    hout[idx] = s;
}

// ---------------- prep: W_ec[l] = eW3[l] @ cW1[l];  c_ec[l] = b3@cW1 + cb1 ----
__global__ void __launch_bounds__(256)
prep_kernel(const float* __restrict__ eW3, const float* __restrict__ eb3,
            const float* __restrict__ cW1, const float* __restrict__ cb1,
            float* __restrict__ W_ec, float* __restrict__ c_ec)
{
    const int l = blockIdx.x;
    const float* A  = eW3 + (size_t)l * H * H;
    const float* Bw = cW1 + (size_t)l * H * H;
    float* O = W_ec + (size_t)l * H * H;
    const int tid = threadIdx.x;
    const int k  = tid >> 1;
    const int jh = (tid & 1) * 64;
    float acc[64];
#pragma unroll
    for (int j = 0; j < 64; ++j) acc[j] = 0.f;
    for (int t = 0; t < H; ++t) {
        const float a = A[k * H + t];
        const float* br = Bw + t * H + jh;
#pragma unroll
        for (int j = 0; j < 64; ++j) acc[j] = fmaf(a, br[j], acc[j]);
    }
#pragma unroll
    for (int j = 0; j < 64; ++j) O[k * H + jh + j] = acc[j];

    if (tid < H) {
        const float* b3 = eb3 + (size_t)l * H;
        float s = cb1[(size_t)l * H + tid];
        for (int t = 0; t < H; ++t) s = fmaf(b3[t], Bw[t * H + tid], s);
        c_ec[(size_t)l * H + tid] = s;
    }
}

// ---------------- per-layer projection: P[n] = [h@eW1a + b1 | h@eW1b] --------
__global__ void __launch_bounds__(256, 4)
proj_kernel(const float* __restrict__ h, const float* __restrict__ eW1,
            const float* __restrict__ eb1, float* __restrict__ P, int NN)
{
    __shared__ float buf[H][LDSTR];
    const int tid  = threadIdx.x;
    const int lane = tid & 63;
    const int q    = tid >> 6;
    const int f2   = lane * 2;
    const int ew   = q * 16;
    const int n0   = blockIdx.x * 64;

    const int nl = n0 + lane;
    const int nc = (nl < NN) ? nl : NN - 1;
    stage_rows(h + (size_t)nc * H + q * 32, q, lane, buf);
    __syncthreads();

    float acc0[16], acc1[16];
    {
        const float2 bv = *(const float2*)&eb1[f2];
#pragma unroll
        for (int i = 0; i < 16; ++i) { acc0[i] = bv.x; acc1[i] = bv.y; }
    }
    gemm_b(buf, eW1, f2, ew, acc0, acc1);                    // P1
#pragma unroll
    for (int i = 0; i < 16; ++i) {
        const int n = n0 + ew + i;
        if (n < NN) {
            float2 v; v.x = acc0[i]; v.y = acc1[i];
            *(float2*)&P[(size_t)n * 256 + f2] = v;
        }
    }
#pragma unroll
    for (int i = 0; i < 16; ++i) { acc0[i] = 0.f; acc1[i] = 0.f; }
    gemm_b(buf, eW1 + (size_t)128 * H, f2, ew, acc0, acc1);  // P2
#pragma unroll
    for (int i = 0; i < 16; ++i) {
        const int n = n0 + ew + i;
        if (n < NN) {
            float2 v; v.x = acc0[i]; v.y = acc1[i];
            *(float2*)&P[(size_t)n * 256 + 128 + f2] = v;
        }
    }
}

// ---------------- per-layer edge kernel (projection-based) ----------------
__global__ void __launch_bounds__(256, 4)
edge_kernel_pre(const float* __restrict__ x, const float* __restrict__ P,
                const int* __restrict__ src, const int* __restrict__ dst,
                const float* __restrict__ eW1,   // for row 256 (d2 weights)
                const float* __restrict__ eW2, const float* __restrict__ eb2,
                const float* __restrict__ eW3, const float* __restrict__ eb3,
                const float* __restrict__ W_ec, const float* __restrict__ c_ec,
                const float* __restrict__ cW2, const float* __restrict__ cb2,
                float* __restrict__ m_aggr, float* __restrict__ dxv,
                int E)
{
    __shared__ float buf[H][LDSTR];
    __shared__ float relx[64], rely[64], relz[64];
    __shared__ int   ssrc[64];
    __shared__ int   evalid[64];

    const int tid  = threadIdx.x;
    const int lane = tid & 63;
    const int q    = tid >> 6;
    const int f2   = lane * 2;
    const int ew   = q * 16;
    const int e0   = blockIdx.x * 64;

    // per-wave geometry (each wave computes its lane's edge; wave 0 publishes)
    int e = e0 + lane;
    const bool ev = (e < E);
    if (!ev) e = E - 1;
    const int s = src[e], d = dst[e];
    const float rx = x[3 * s + 0] - x[3 * d + 0];
    const float ry = x[3 * s + 1] - x[3 * d + 1];
    const float rz = x[3 * s + 2] - x[3 * d + 2];
    const float d2 = rx * rx + ry * ry + rz * rz;
    if (q == 0) {
        ssrc[lane] = s; evalid[lane] = ev ? 1 : 0;
        relx[lane] = rx; rely[lane] = ry; relz[lane] = rz;
    }

    // stage m1 = silu(P1[s] + P2[d] + d2*w256) ; lane = edge, wave = feature slice
    {
        const float* p1  = P + (size_t)s * 256 + q * 32;
        const float* p2  = P + (size_t)d * 256 + 128 + q * 32;
        const float* w2r = eW1 + (size_t)256 * H + q * 32;
#pragma unroll
        for (int hh = 0; hh < 2; ++hh) {
            float4 a[4], b[4], w[4];
#pragma unroll
            for (int c = 0; c < 4; ++c) {
                a[c] = *(const float4*)(p1 + 16 * hh + 4 * c);
                b[c] = *(const float4*)(p2 + 16 * hh + 4 * c);
                w[c] = *(const float4*)(w2r + 16 * hh + 4 * c);
            }
#pragma unroll
            for (int c = 0; c < 4; ++c) {
                const int f = q * 32 + 16 * hh + 4 * c;
                buf[f + 0][lane] = silu_f(fmaf(d2, w[c].x, a[c].x + b[c].x));
                buf[f + 1][lane] = silu_f(fmaf(d2, w[c].y, a[c].y + b[c].y));
                buf[f + 2][lane] = silu_f(fmaf(d2, w[c].z, a[c].z + b[c].z));
                buf[f + 3][lane] = silu_f(fmaf(d2, w[c].w, a[c].w + b[c].w));
            }
        }
    }
    __syncthreads();                                   // (1) m1 ready

    float acc0[16], acc1[16];
    {
        const float2 bv = *(const float2*)&eb2[f2];
#pragma unroll
        for (int i = 0; i < 16; ++i) { acc0[i] = bv.x; acc1[i] = bv.y; }
    }
    gemm_b(buf, eW2, f2, ew, acc0, acc1);
    __syncthreads();                                   // (2) all reads of m1 done
    writeback<true>(buf, f2, ew, acc0, acc1);          // m2
    __syncthreads();                                   // (3) m2 ready

    {
        const float2 bv = *(const float2*)&eb3[f2];
#pragma unroll
        for (int i = 0; i < 16; ++i) { acc0[i] = bv.x; acc1[i] = bv.y; }
    }
    gemm_b(buf, eW3, f2, ew, acc0, acc1);              // m (regs only)

    // scatter m into m_aggr[src]
#pragma unroll
    for (int i = 0; i < 16; ++i) {
        const int ee = ew + i;
        if (evalid[ee]) {
            float* dp = &m_aggr[(size_t)ssrc[ee] * H + f2];
            atomicAdd(dp + 0, acc0[i]);
            atomicAdd(dp + 1, acc1[i]);
        }
    }

    // coord: c1 = m2 @ W_ec + c_ec  (m2 still in LDS, no barrier needed)
    {
        const float2 bv = *(const float2*)&c_ec[f2];
#pragma unroll
        for (int i = 0; i < 16; ++i) { acc0[i] = bv.x; acc1[i] = bv.y; }
    }
    gemm_b(buf, W_ec, f2, ew, acc0, acc1);

    {
        const float2 c2 = *(const float2*)&cW2[f2];
        float p[16];
#pragma unroll
        for (int i = 0; i < 16; ++i)
            p[i] = fmaf(silu_f(acc0[i]), c2.x, silu_f(acc1[i]) * c2.y);
#pragma unroll
        for (int msk = 1; msk < 64; msk <<= 1)
#pragma unroll
            for (int i = 0; i < 16; ++i)
                p[i] += __shfl_xor(p[i], msk);
        float myp = 0.f;
#pragma unroll
        for (int i = 0; i < 16; ++i) myp = (lane == i) ? p[i] : myp;
        if (lane < 16) {
            const int ee = ew + lane;
            if (evalid[ee]) {
                const float coef = tanhf(myp + cb2[0]);
                float* dp = &dxv[(size_t)ssrc[ee] * 3];
                atomicAdd(dp + 0, relx[ee] * coef);
                atomicAdd(dp + 1, rely[ee] * coef);
                atomicAdd(dp + 2, relz[ee] * coef);
            }
        }
    }
}

// ---------------- fallback edge kernel (round-5, no P buffer) ----------------
__global__ void __launch_bounds__(256, 4)
edge_kernel(const float* __restrict__ x, const float* __restrict__ h,
            const int* __restrict__ src, const int* __restrict__ dst,
            const float* __restrict__ eW1, const float* __restrict__ eb1,
            const float* __restrict__ eW2, const float* __restrict__ eb2,
            const float* __restrict__ eW3, const float* __restrict__ eb3,
            const float* __restrict__ cW1, const float* __restrict__ cb1,
            const float* __restrict__ cW2, const float* __restrict__ cb2,
            float* __restrict__ m_aggr, float* __restrict__ dxv,
            int E)
{
    __shared__ float buf[H][LDSTR];
    __shared__ float d2s[64];
    __shared__ float relx[64], rely[64], relz[64];
    __shared__ int   ssrc[64], sdst[64];
    __shared__ int   evalid[64];

    const int tid  = threadIdx.x;
    const int lane = tid & 63;
    const int q    = tid >> 6;
    const int f2   = lane * 2;
    const int ew   = q * 16;
    const int e0   = blockIdx.x * 64;

    if (tid < 64) {
        int e = e0 + tid;
        int v = (e < E) ? 1 : 0;
        if (!v) e = E - 1;
        evalid[tid] = v;
        const int s = src[e], d = dst[e];
        ssrc[tid] = s; sdst[tid] = d;
        const float rx = x[3 * s + 0] - x[3 * d + 0];
        const float ry = x[3 * s + 1] - x[3 * d + 1];
        const float rz = x[3 * s + 2] - x[3 * d + 2];
        relx[tid] = rx; rely[tid] = ry; relz[tid] = rz;
        d2s[tid] = rx * rx + ry * ry + rz * rz;
    }
    __syncthreads();

    float4 pre[8];
    prefetch_row(h + (size_t)sdst[lane] * H + q * 32, pre);
    stage_rows(h + (size_t)ssrc[lane] * H + q * 32, q, lane, buf);
    __syncthreads();

    float acc0[16], acc1[16];
    {
        const float2 bv = *(const float2*)&eb1[f2];
        const float2 wd = *(const float2*)&eW1[(size_t)256 * H + f2];
#pragma unroll
        for (int i = 0; i < 16; ++i) {
            const float d2 = d2s[ew + i];
            acc0[i] = fmaf(d2, wd.x, bv.x);
            acc1[i] = fmaf(d2, wd.y, bv.y);
        }
    }
    gemm_b(buf, eW1, f2, ew, acc0, acc1);
    __syncthreads();
    store_pre(pre, q, lane, buf);
    __syncthreads();
    gemm_b(buf, eW1 + (size_t)128 * H, f2, ew, acc0, acc1);
    __syncthreads();

    writeback<true>(buf, f2, ew, acc0, acc1);
    __syncthreads();

    {
        const float2 bv = *(const float2*)&eb2[f2];
#pragma unroll
        for (int i = 0; i < 16; ++i) { acc0[i] = bv.x; acc1[i] = bv.y; }
    }
    gemm_b(buf, eW2, f2, ew, acc0, acc1);
    __syncthreads();
    writeback<true>(buf, f2, ew, acc0, acc1);
    __syncthreads();

    {
        const float2 bv = *(const float2*)&eb3[f2];
#pragma unroll
        for (int i = 0; i < 16; ++i) { acc0[i] = bv.x; acc1[i] = bv.y; }
    }
    gemm_b(buf, eW3, f2, ew, acc0, acc1);

#pragma unroll
    for (int i = 0; i < 16; ++i) {
        const int e2 = ew + i;
        if (evalid[e2]) {
            float* dp = &m_aggr[(size_t)ssrc[e2] * H + f2];
            atomicAdd(dp + 0, acc0[i]);
            atomicAdd(dp + 1, acc1[i]);
        }
    }
    __syncthreads();
    writeback<false>(buf, f2, ew, acc0, acc1);
    __syncthreads();

    {
        const float2 bv = *(const float2*)&cb1[f2];
#pragma unroll
        for (int i = 0; i < 16; ++i) { acc0[i] = bv.x; acc1[i] = bv.y; }
    }
    gemm_b(buf, cW1, f2, ew, acc0, acc1);

    {
        const float2 c2 = *(const float2*)&cW2[f2];
        float p[16];
#pragma unroll
        for (int i = 0; i < 16; ++i)
            p[i] = fmaf(silu_f(acc0[i]), c2.x, silu_f(acc1[i]) * c2.y);
#pragma unroll
        for (int msk = 1; msk < 64; msk <<= 1)
#pragma unroll
            for (int i = 0; i < 16; ++i)
                p[i] += __shfl_xor(p[i], msk);
        float myp = 0.f;
#pragma unroll
        for (int i = 0; i < 16; ++i) myp = (lane == i) ? p[i] : myp;
        if (lane < 16) {
            const int e2 = ew + lane;
            if (evalid[e2]) {
                const float coef = tanhf(myp + cb2[0]);
                float* dp = &dxv[(size_t)ssrc[e2] * 3];
                atomicAdd(dp + 0, relx[e2] * coef);
                atomicAdd(dp + 1, rely[e2] * coef);
                atomicAdd(dp + 2, relz[e2] * coef);
            }
        }
    }
}

// ---------------- per-layer node kernel ----------------
__global__ void __launch_bounds__(256, 4)
node_kernel(float* __restrict__ x, const float* __restrict__ dxv,
            float* __restrict__ h, const float* __restrict__ m_aggr,
            const float* __restrict__ nW1, const float* __restrict__ nb1,
            const float* __restrict__ nW2, const float* __restrict__ nb2,
            const float* __restrict__ nW3, const float* __restrict__ nb3,
            int NN)
{
    __shared__ float buf[H][LDSTR];

    const int tid  = threadIdx.x;
    const int lane = tid & 63;
    const int q    = tid >> 6;
    const int f2   = lane * 2;
    const int ew   = q * 16;
    const int n0   = blockIdx.x * 64;

    const int nl = n0 + lane;
    const int nc = (nl < NN) ? nl : NN - 1;

    if (tid < 192) {
        const int nn = n0 + tid / 3;
        if (nn < NN) {
            const int c = tid % 3;
            x[(size_t)nn * 3 + c] += dxv[(size_t)nn * 3 + c];
        }
    }

    float4 pre[8];
    prefetch_row(m_aggr + (size_t)nc * H + q * 32, pre);
    stage_rows(h + (size_t)nc * H + q * 32, q, lane, buf);
    __syncthreads();

    float acc0[16], acc1[16];
    {
        const float2 bv = *(const float2*)&nb1[f2];
#pragma unroll
        for (int i = 0; i < 16; ++i) { acc0[i] = bv.x; acc1[i] = bv.y; }
    }
    gemm_b(buf, nW1, f2, ew, acc0, acc1);
    __syncthreads();
    store_pre(pre, q, lane, buf);
    __syncthreads();
    gemm_b(buf, nW1 + (size_t)128 * H, f2, ew, acc0, acc1);
    __syncthreads();

    writeback<true>(buf, f2, ew, acc0, acc1);
    __syncthreads();

    {
        const float2 bv = *(const float2*)&nb2[f2];
#pragma unroll
        for (int i = 0; i < 16; ++i) { acc0[i] = bv.x; acc1[i] = bv.y; }
    }
    gemm_b(buf, nW2, f2, ew, acc0, acc1);
    __syncthreads();
    writeback<true>(buf, f2, ew, acc0, acc1);
    __syncthreads();

    {
        const float2 bv = *(const float2*)&nb3[f2];
#pragma unroll
        for (int i = 0; i < 16; ++i) { acc0[i] = bv.x; acc1[i] = bv.y; }
    }
    gemm_b(buf, nW3, f2, ew, acc0, acc1);

#pragma unroll
    for (int i = 0; i < 16; ++i) {
        const int n = n0 + ew + i;
        if (n < NN) {
            float2* hp = (float2*)&h[(size_t)n * H + f2];
            float2 v = *hp;
            v.x += acc0[i]; v.y += acc1[i];
            *hp = v;
        }
    }
}

// ---------------- readout ----------------
__global__ void __launch_bounds__(256, 4)
readout_kernel(const float* __restrict__ h, const float* __restrict__ W_ro,
               const float* __restrict__ b_ro, float* __restrict__ out, int NN)
{
    __shared__ float buf[H][LDSTR];
    __shared__ float sred[4][H];

    const int tid  = threadIdx.x;
    const int lane = tid & 63;
    const int q    = tid >> 6;
    const int f2   = lane * 2;
    const int ew   = q * 16;
    const int n0   = blockIdx.x * 64;

    const int nl = n0 + lane;
    const int nc = (nl < NN) ? nl : NN - 1;

    stage_rows(h + (size_t)nc * H + q * 32, q, lane, buf);
    __syncthreads();

    float acc0[16], acc1[16];
    {
        const float2 bv = *(const float2*)&b_ro[f2];
#pragma unroll
        for (int i = 0; i < 16; ++i) { acc0[i] = bv.x; acc1[i] = bv.y; }
    }
    gemm_b(buf, W_ro, f2, ew, acc0, acc1);

    float* zn = out + H;
    float s0 = 0.f, s1 = 0.f;
#pragma unroll
    for (int i = 0; i < 16; ++i) {
        const int n = n0 + ew + i;
        if (n < NN) {
            float2 v; v.x = acc0[i]; v.y = acc1[i];
            *(float2*)&zn[(size_t)n * H + f2] = v;
            s0 += acc0[i]; s1 += acc1[i];
        }
    }
    sred[q][f2 + 0] = s0;
    sred[q][f2 + 1] = s1;
    __syncthreads();
    if (tid < H) {
        const float inv = 1.0f / (float)NN;
        const float v = (sred[0][tid] + sred[1][tid] + sred[2][tid] + sred[3][tid]) * inv;
        atomicAdd(&out[tid], v);
    }
}

extern "C" void kernel_launch(void* const* d_in, const int* in_sizes, int n_in,
                              void* d_out, int out_size, void* d_ws, size_t ws_size,
                              hipStream_t stream) {
    const float* node_pos    = (const float*)d_in[0];
    const float* node_scalar = (const float*)d_in[1];
    const int*   type_ids    = (const int*)d_in[2];
    const int*   edge_index  = (const int*)d_in[3];
    const float* emb         = (const float*)d_in[4];
    const float* W_in        = (const float*)d_in[5];
    const float* b_in        = (const float*)d_in[6];
    const float* eW1 = (const float*)d_in[7];
    const float* eb1 = (const float*)d_in[8];
    const float* eW2 = (const float*)d_in[9];
    const float* eb2 = (const float*)d_in[10];
    const float* eW3 = (const float*)d_in[11];
    const float* eb3 = (const float*)d_in[12];
    const float* cW1 = (const float*)d_in[13];
    const float* cb1 = (const float*)d_in[14];
    const float* cW2 = (const float*)d_in[15];
    const float* cb2 = (const float*)d_in[16];
    const float* nW1 = (const float*)d_in[17];
    const float* nb1 = (const float*)d_in[18];
    const float* nW2 = (const float*)d_in[19];
    const float* nb2 = (const float*)d_in[20];
    const float* nW3 = (const float*)d_in[21];
    const float* nb3 = (const float*)d_in[22];
    const float* W_ro = (const float*)d_in[23];
    const float* b_ro = (const float*)d_in[24];

    const int NN = in_sizes[0] / 3;
    const int E  = in_sizes[3] / 2;
    const int Lc = in_sizes[7] / ((2 * H + 1) * H);
    const int ntypes = in_sizes[4] / 8;

    const int* srcp = edge_index;
    const int* dstp = edge_index + E;

    float* hbuf = (float*)d_out + H;           // h lives in the z_nodes slot

    // ws layout (projection path): P | m_aggr | xb | dxb | W_ec | c_ec
    const size_t fl_P  = (size_t)NN * 256;
    const size_t fl_ma = (size_t)NN * H;
    const size_t fl_x  = (size_t)NN * 3;
    const size_t fl_We = (size_t)Lc * H * H;
    const size_t fl_ce = (size_t)Lc * H;
    const size_t need  = (fl_P + fl_ma + 2 * fl_x + fl_We + fl_ce) * sizeof(float);
    const bool use_proj = (ws_size >= need);

    float* ws = (float*)d_ws;
    float *P, *m_aggr, *xb, *dxb, *W_ec, *c_ec;
    if (use_proj) {
        P      = ws;
        m_aggr = P + fl_P;
        xb     = m_aggr + fl_ma;
        dxb    = xb + fl_x;
        W_ec   = dxb + fl_x;
        c_ec   = W_ec + fl_We;
    } else {
        P = W_ec = c_ec = nullptr;
        m_aggr = ws;
        xb     = m_aggr + fl_ma;
        dxb    = xb + fl_x;
    }

    hipMemcpyAsync(xb, node_pos, sizeof(float) * 3 * (size_t)NN,
                   hipMemcpyDeviceToDevice, stream);
    input_kernel<<<dim3((NN * H + 255) / 256), dim3(256), 0, stream>>>(
        node_scalar, type_ids, emb, W_in, b_in, hbuf, NN, ntypes);

    if (use_proj)
        prep_kernel<<<dim3(Lc), dim3(256), 0, stream>>>(eW3, eb3, cW1, cb1, W_ec, c_ec);

    for (int l = 0; l < Lc; ++l) {
        hipMemsetAsync(m_aggr, 0, sizeof(float) * (size_t)NN * H, stream);
        hipMemsetAsync(dxb, 0, sizeof(float) * (size_t)NN * 3, stream);
        if (use_proj) {
            proj_kernel<<<dim3((NN + 63) / 64), dim3(256), 0, stream>>>(
                hbuf, eW1 + (size_t)l * (2 * H + 1) * H, eb1 + (size_t)l * H, P, NN);
            edge_kernel_pre<<<dim3((E + 63) / 64), dim3(256), 0, stream>>>(
                xb, P, srcp, dstp,
                eW1 + (size_t)l * (2 * H + 1) * H,
                eW2 + (size_t)l * H * H, eb2 + (size_t)l * H,
                eW3 + (size_t)l * H * H, eb3 + (size_t)l * H,
                W_ec + (size_t)l * H * H, c_ec + (size_t)l * H,
                cW2 + (size_t)l * H, cb2 + l,
                m_aggr, dxb, E);
        } else {
            edge_kernel<<<dim3((E + 63) / 64), dim3(256), 0, stream>>>(
                xb, hbuf, srcp, dstp,
                eW1 + (size_t)l * (2 * H + 1) * H, eb1 + (size_t)l * H,
                eW2 + (size_t)l * H * H,           eb2 + (size_t)l * H,
                eW3 + (size_t)l * H * H,           eb3 + (size_t)l * H,
                cW1 + (size_t)l * H * H,           cb1 + (size_t)l * H,
                cW2 + (size_t)l * H,               cb2 + l,
                m_aggr, dxb, E);
        }
        node_kernel<<<dim3((NN + 63) / 64), dim3(256), 0, stream>>>(
            xb, dxb, hbuf, m_aggr,
            nW1 + (size_t)l * 2 * H * H, nb1 + (size_t)l * H,
            nW2 + (size_t)l * H * H,     nb2 + (size_t)l * H,
            nW3 + (size_t)l * H * H,     nb3 + (size_t)l * H, NN);
    }

    hipMemsetAsync(d_out, 0, sizeof(float) * H, stream);
    readout_kernel<<<dim3((NN + 63) / 64), dim3(256), 0, stream>>>(
        hbuf, W_ro, b_ro, (float*)d_out, NN);
}